// Round 1
// baseline (3026.605 us; speedup 1.0000x reference)
//
#include <hip/hip_runtime.h>

#define NC 200000
#define NM 50000
#define NE 1000000
#define DF 64   // feature dim (D == H == 64)

// ---------------- count kernel: cnt[dst[e]] += 1 ----------------
__global__ __launch_bounds__(256) void count_k(const int* __restrict__ dst,
                                               float* __restrict__ cnt, int n_edges) {
    int tid = blockIdx.x * blockDim.x + threadIdx.x;
    for (int e = tid; e < n_edges; e += gridDim.x * blockDim.x) {
        atomicAdd(&cnt[dst[e]], 1.0f);
    }
}

// ---------------- scatter: agg[dst[e]] += xsrc[src[e]] ----------------
// 16 threads per edge, float4 each.
__global__ __launch_bounds__(256) void scatter_add(const float* __restrict__ xsrc,
                                                   const int* __restrict__ src,
                                                   const int* __restrict__ dst,
                                                   float* __restrict__ agg, int n_edges) {
    int tid = blockIdx.x * blockDim.x + threadIdx.x;
    int e = tid >> 4;
    if (e >= n_edges) return;
    int q = (tid & 15) * 4;
    int s = src[e];
    int d = dst[e];
    const float4 v = *reinterpret_cast<const float4*>(xsrc + (long)s * DF + q);
    float* p = agg + (long)d * DF + q;
    atomicAdd(p + 0, v.x);
    atomicAdd(p + 1, v.y);
    atomicAdd(p + 2, v.z);
    atomicAdd(p + 3, v.w);
}

// ---------------- dense1: h = relu((agg/cnt) @ Wl + x @ Wr + b) ----------------
// 256 threads = 4 nodes x 64 output features; weights staged in LDS; grid-stride.
__global__ __launch_bounds__(256) void dense1_k(const float* __restrict__ agg,
                                                const float* __restrict__ cnt,
                                                const float* __restrict__ xdst,
                                                const float* __restrict__ Wl,
                                                const float* __restrict__ Wr,
                                                const float* __restrict__ b,
                                                float* __restrict__ hout, int n_nodes) {
    __shared__ float sWl[DF * DF];
    __shared__ float sWr[DF * DF];
    __shared__ float sAgg[4][DF];
    __shared__ float sX[4][DF];
    const int t = threadIdx.x;
    for (int i = t; i < DF * DF; i += 256) {
        sWl[i] = Wl[i];
        sWr[i] = Wr[i];
    }
    const int ln = t >> 6;   // local node 0..3
    const int j = t & 63;    // output feature
    const float bj = b[j];
    for (int node0 = blockIdx.x * 4; node0 < n_nodes; node0 += gridDim.x * 4) {
        const int node = node0 + ln;  // n_nodes % 4 == 0 always here
        __syncthreads();              // covers weight load (iter 0) + prev-iter reads
        sAgg[ln][j] = agg[(long)node * DF + j];
        sX[ln][j] = xdst[(long)node * DF + j];
        __syncthreads();
        const float inv = 1.0f / fmaxf(cnt[node], 1.0f);
        float acc = bj;
#pragma unroll
        for (int k = 0; k < DF; ++k) {
            acc = fmaf(sAgg[ln][k] * inv, sWl[k * DF + j], acc);
            acc = fmaf(sX[ln][k], sWr[k * DF + j], acc);
        }
        hout[(long)node * DF + j] = fmaxf(acc, 0.0f);  // relu
    }
}

// ---------------- dense2 + final linear fused ----------------
// h2 = (agg/cnt) @ Wl + hc @ Wr + b  (no relu); out = h2 @ Wlin + blin
__global__ __launch_bounds__(256) void dense2_k(const float* __restrict__ agg,
                                                const float* __restrict__ cnt,
                                                const float* __restrict__ hc,
                                                const float* __restrict__ Wl,
                                                const float* __restrict__ Wr,
                                                const float* __restrict__ b,
                                                const float* __restrict__ Wlin,
                                                const float* __restrict__ blin,
                                                float* __restrict__ out, int n_nodes) {
    __shared__ float sWl[DF * DF];
    __shared__ float sWr[DF * DF];
    __shared__ float sAgg[4][DF];
    __shared__ float sH[4][DF];
    const int t = threadIdx.x;
    for (int i = t; i < DF * DF; i += 256) {
        sWl[i] = Wl[i];
        sWr[i] = Wr[i];
    }
    const int ln = t >> 6;
    const int j = t & 63;
    const float bj = b[j];
    const float wl0 = Wlin[j * 2 + 0];
    const float wl1 = Wlin[j * 2 + 1];
    const float bl0 = blin[0];
    const float bl1 = blin[1];
    for (int node0 = blockIdx.x * 4; node0 < n_nodes; node0 += gridDim.x * 4) {
        const int node = node0 + ln;
        __syncthreads();
        sAgg[ln][j] = agg[(long)node * DF + j];
        sH[ln][j] = hc[(long)node * DF + j];
        __syncthreads();
        const float inv = 1.0f / fmaxf(cnt[node], 1.0f);
        float acc = bj;
#pragma unroll
        for (int k = 0; k < DF; ++k) {
            acc = fmaf(sAgg[ln][k] * inv, sWl[k * DF + j], acc);
            acc = fmaf(sH[ln][k], sWr[k * DF + j], acc);
        }
        // fused final linear: out[node] = h2row @ Wlin + blin ; reduce across the wave
        float r0 = acc * wl0;
        float r1 = acc * wl1;
#pragma unroll
        for (int off = 32; off > 0; off >>= 1) {
            r0 += __shfl_xor(r0, off);
            r1 += __shfl_xor(r1, off);
        }
        if (j == 0) {
            out[(long)node * 2 + 0] = r0 + bl0;
            out[(long)node * 2 + 1] = r1 + bl1;
        }
    }
}

extern "C" void kernel_launch(void* const* d_in, const int* in_sizes, int n_in,
                              void* d_out, int out_size, void* d_ws, size_t ws_size,
                              hipStream_t stream) {
    const float* x_c = (const float*)d_in[0];
    const float* x_m = (const float*)d_in[1];
    const int* cm_src = (const int*)d_in[2];
    const int* cm_dst = (const int*)d_in[3];
    const int* mc_src = (const int*)d_in[4];
    const int* mc_dst = (const int*)d_in[5];
    const float* Wl1_cm = (const float*)d_in[6];
    const float* Wr1_cm = (const float*)d_in[7];
    const float* b1_cm = (const float*)d_in[8];
    const float* Wl1_mc = (const float*)d_in[9];
    const float* Wr1_mc = (const float*)d_in[10];
    const float* b1_mc = (const float*)d_in[11];
    // layer-2 cm weights (d_in[12..14]) are dead: h2_m is unused in the reference
    const float* Wl2_mc = (const float*)d_in[15];
    const float* Wr2_mc = (const float*)d_in[16];
    const float* b2_mc = (const float*)d_in[17];
    const float* W_lin = (const float*)d_in[18];
    const float* b_lin = (const float*)d_in[19];
    float* out = (float*)d_out;

    // workspace layout (floats):
    // agg_m [NM*64] | cnt_m [NM] | cnt_c [NC] | agg_c [NC*64] | h_m [NM*64] | h_c [NC*64]
    float* ws = (float*)d_ws;
    float* agg_m = ws;
    float* cnt_m = agg_m + (long)NM * DF;
    float* cnt_c = cnt_m + NM;
    float* agg_c = cnt_c + NC;
    float* h_m = agg_c + (long)NC * DF;
    float* h_c = h_m + (long)NM * DF;

    // zero agg_m, cnt_m, cnt_c, agg_c (contiguous block)
    size_t zero_bytes = ((long)NM * DF + NM + NC + (long)NC * DF) * sizeof(float);
    hipMemsetAsync(agg_m, 0, zero_bytes, stream);

    // counts (same dst arrays reused in layer 2, so counts are shared)
    count_k<<<1024, 256, 0, stream>>>(cm_dst, cnt_m, NE);
    count_k<<<1024, 256, 0, stream>>>(mc_dst, cnt_c, NE);

    // layer 1 scatters
    const int scat_blocks = (NE * 16) / 256;  // 62500
    scatter_add<<<scat_blocks, 256, 0, stream>>>(x_c, cm_src, cm_dst, agg_m, NE);
    scatter_add<<<scat_blocks, 256, 0, stream>>>(x_m, mc_src, mc_dst, agg_c, NE);

    // layer 1 dense
    dense1_k<<<1024, 256, 0, stream>>>(agg_m, cnt_m, x_m, Wl1_cm, Wr1_cm, b1_cm, h_m, NM);
    dense1_k<<<2048, 256, 0, stream>>>(agg_c, cnt_c, x_c, Wl1_mc, Wr1_mc, b1_mc, h_c, NC);

    // layer 2: re-zero agg_c, scatter h_m over mc edges, fused dense2+linear
    hipMemsetAsync(agg_c, 0, (long)NC * DF * sizeof(float), stream);
    scatter_add<<<scat_blocks, 256, 0, stream>>>(h_m, mc_src, mc_dst, agg_c, NE);
    dense2_k<<<2048, 256, 0, stream>>>(agg_c, cnt_c, h_c, Wl2_mc, Wr2_mc, b2_mc,
                                       W_lin, b_lin, out, NC);
}

// Round 2
// 1297.437 us; speedup vs baseline: 2.3328x; 2.3328x over previous
//
#include <hip/hip_runtime.h>

#define NC 200000
#define NM 50000
#define NE 1000000
#define DF 64   // feature dim (D == H == 64)

// ---------------- histogram: bins[dst[e]] += 1 (int atomics) ----------------
__global__ __launch_bounds__(256) void hist_k(const int* __restrict__ dst,
                                              int* __restrict__ bins, int n_edges) {
    int tid = blockIdx.x * blockDim.x + threadIdx.x;
    for (int e = tid; e < n_edges; e += gridDim.x * blockDim.x) {
        atomicAdd(&bins[dst[e]], 1);
    }
}

// ---------------- single-block exclusive scan over n bins -> start[n+1] ----------------
__global__ __launch_bounds__(1024) void scan_k(const int* __restrict__ bins,
                                               int* __restrict__ start, int n) {
    __shared__ int sums[1024];
    const int t = threadIdx.x;
    const int chunk = (n + 1023) / 1024;
    const int lo = t * chunk;
    const int hi = min(lo + chunk, n);
    int s = 0;
    for (int i = lo; i < hi; ++i) s += bins[i];
    sums[t] = s;
    __syncthreads();
    // Hillis-Steele inclusive scan over 1024 partials
    for (int off = 1; off < 1024; off <<= 1) {
        int v = 0;
        if (t >= off) v = sums[t - off];
        __syncthreads();
        if (t >= off) sums[t] += v;
        __syncthreads();
    }
    int run = (t == 0) ? 0 : sums[t - 1];
    for (int i = lo; i < hi; ++i) {
        start[i] = run;
        run += bins[i];
    }
    if (t == 1023) start[n] = sums[1023];
}

// ---------------- placement: sorted_src[start[d] + cur[d]++] = src[e] ----------------
__global__ __launch_bounds__(256) void place_k(const int* __restrict__ src,
                                               const int* __restrict__ dst,
                                               const int* __restrict__ start,
                                               int* __restrict__ cur,
                                               int* __restrict__ sorted_src, int n_edges) {
    int tid = blockIdx.x * blockDim.x + threadIdx.x;
    for (int e = tid; e < n_edges; e += gridDim.x * blockDim.x) {
        int d = dst[e];
        int pos = start[d] + atomicAdd(&cur[d], 1);
        sorted_src[pos] = src[e];
    }
}

// ---------------- aggregation: one wave per dst node, lane = feature ----------------
// writes the MEAN row directly (no atomics, no count array needed)
__global__ __launch_bounds__(256) void agg_k(const float* __restrict__ x,
                                             const int* __restrict__ start,
                                             const int* __restrict__ sorted_src,
                                             float* __restrict__ aggmean, int n_nodes) {
    const int wid = (blockIdx.x * blockDim.x + threadIdx.x) >> 6;
    const int lane = threadIdx.x & 63;
    const int nwaves = (gridDim.x * blockDim.x) >> 6;
    for (int n = wid; n < n_nodes; n += nwaves) {
        const int s0 = start[n];
        const int s1 = start[n + 1];
        float acc = 0.0f;
        for (int e = s0; e < s1; ++e) {
            int s = sorted_src[e];  // wave-uniform -> broadcast load
            acc += x[(long)s * DF + lane];
        }
        const float inv = 1.0f / fmaxf((float)(s1 - s0), 1.0f);
        aggmean[(long)n * DF + lane] = acc * inv;
    }
}

// ---------------- dense1: h = relu(mean @ Wl + x @ Wr + b) ----------------
// 256 threads = 4 nodes x 64 output features; weights staged in LDS; grid-stride.
// hout may alias mean (per-row read-then-write within one block only).
__global__ __launch_bounds__(256) void dense1_k(const float* __restrict__ mean,
                                                const float* __restrict__ xdst,
                                                const float* __restrict__ Wl,
                                                const float* __restrict__ Wr,
                                                const float* __restrict__ b,
                                                float* __restrict__ hout, int n_nodes) {
    __shared__ float sWl[DF * DF];
    __shared__ float sWr[DF * DF];
    __shared__ float sAgg[4][DF];
    __shared__ float sX[4][DF];
    const int t = threadIdx.x;
    for (int i = t; i < DF * DF; i += 256) {
        sWl[i] = Wl[i];
        sWr[i] = Wr[i];
    }
    const int ln = t >> 6;   // local node 0..3
    const int j = t & 63;    // output feature
    const float bj = b[j];
    for (int node0 = blockIdx.x * 4; node0 < n_nodes; node0 += gridDim.x * 4) {
        const int node = node0 + ln;
        __syncthreads();              // covers weight load (iter 0) + prev-iter reads
        sAgg[ln][j] = mean[(long)node * DF + j];
        sX[ln][j] = xdst[(long)node * DF + j];
        __syncthreads();
        float acc = bj;
#pragma unroll
        for (int k = 0; k < DF; ++k) {
            acc = fmaf(sAgg[ln][k], sWl[k * DF + j], acc);
            acc = fmaf(sX[ln][k], sWr[k * DF + j], acc);
        }
        hout[(long)node * DF + j] = fmaxf(acc, 0.0f);  // relu
    }
}

// ---------------- dense2 + final linear fused ----------------
// h2 = mean @ Wl + hc @ Wr + b  (no relu); out = h2 @ Wlin + blin
__global__ __launch_bounds__(256) void dense2_k(const float* __restrict__ mean,
                                                const float* __restrict__ hc,
                                                const float* __restrict__ Wl,
                                                const float* __restrict__ Wr,
                                                const float* __restrict__ b,
                                                const float* __restrict__ Wlin,
                                                const float* __restrict__ blin,
                                                float* __restrict__ out, int n_nodes) {
    __shared__ float sWl[DF * DF];
    __shared__ float sWr[DF * DF];
    __shared__ float sAgg[4][DF];
    __shared__ float sH[4][DF];
    const int t = threadIdx.x;
    for (int i = t; i < DF * DF; i += 256) {
        sWl[i] = Wl[i];
        sWr[i] = Wr[i];
    }
    const int ln = t >> 6;
    const int j = t & 63;
    const float bj = b[j];
    const float wl0 = Wlin[j * 2 + 0];
    const float wl1 = Wlin[j * 2 + 1];
    const float bl0 = blin[0];
    const float bl1 = blin[1];
    for (int node0 = blockIdx.x * 4; node0 < n_nodes; node0 += gridDim.x * 4) {
        const int node = node0 + ln;
        __syncthreads();
        sAgg[ln][j] = mean[(long)node * DF + j];
        sH[ln][j] = hc[(long)node * DF + j];
        __syncthreads();
        float acc = bj;
#pragma unroll
        for (int k = 0; k < DF; ++k) {
            acc = fmaf(sAgg[ln][k], sWl[k * DF + j], acc);
            acc = fmaf(sH[ln][k], sWr[k * DF + j], acc);
        }
        // fused final linear: out[node] = h2row @ Wlin + blin ; reduce across the wave
        float r0 = acc * wl0;
        float r1 = acc * wl1;
#pragma unroll
        for (int off = 32; off > 0; off >>= 1) {
            r0 += __shfl_xor(r0, off);
            r1 += __shfl_xor(r1, off);
        }
        if (j == 0) {
            out[(long)node * 2 + 0] = r0 + bl0;
            out[(long)node * 2 + 1] = r1 + bl1;
        }
    }
}

extern "C" void kernel_launch(void* const* d_in, const int* in_sizes, int n_in,
                              void* d_out, int out_size, void* d_ws, size_t ws_size,
                              hipStream_t stream) {
    const float* x_c = (const float*)d_in[0];
    const float* x_m = (const float*)d_in[1];
    const int* cm_src = (const int*)d_in[2];
    const int* cm_dst = (const int*)d_in[3];
    const int* mc_src = (const int*)d_in[4];
    const int* mc_dst = (const int*)d_in[5];
    const float* Wl1_cm = (const float*)d_in[6];
    const float* Wr1_cm = (const float*)d_in[7];
    const float* b1_cm = (const float*)d_in[8];
    const float* Wl1_mc = (const float*)d_in[9];
    const float* Wr1_mc = (const float*)d_in[10];
    const float* b1_mc = (const float*)d_in[11];
    // layer-2 cm weights (d_in[12..14]) are dead: h2_m is unused in the reference
    const float* Wl2_mc = (const float*)d_in[15];
    const float* Wr2_mc = (const float*)d_in[16];
    const float* b2_mc = (const float*)d_in[17];
    const float* W_lin = (const float*)d_in[18];
    const float* b_lin = (const float*)d_in[19];
    float* out = (float*)d_out;

    // ---- workspace layout ----
    // floats: agg_m [NM*64] (h_m aliases), h_c [NC*64], agg_c [NC*64]
    // ints:   binsM[NM] binsC[NC] curM[NM] curC[NC] startM[NM+1] startC[NC+1]
    //         srt_cm[NE] srt_mc[NE]
    float* ws = (float*)d_ws;
    float* agg_m = ws;                             // layer-1 m-mean, then h_m (aliased)
    float* h_c = agg_m + (long)NM * DF;
    float* agg_c = h_c + (long)NC * DF;            // layer-1 c-mean, reused for layer-2 c-mean
    int* ip = (int*)(agg_c + (long)NC * DF);
    int* binsM = ip;
    int* binsC = binsM + NM;
    int* curM = binsC + NC;
    int* curC = curM + NM;
    int* startM = curC + NC;
    int* startC = startM + (NM + 1);
    int* srt_cm = startC + (NC + 1);
    int* srt_mc = srt_cm + NE;

    // zero bins + cursors (contiguous)
    hipMemsetAsync(binsM, 0, (size_t)(2 * (NM + NC)) * sizeof(int), stream);

    // build CSR grouping by destination for both edge types
    hist_k<<<2048, 256, 0, stream>>>(cm_dst, binsM, NE);
    hist_k<<<2048, 256, 0, stream>>>(mc_dst, binsC, NE);
    scan_k<<<1, 1024, 0, stream>>>(binsM, startM, NM);
    scan_k<<<1, 1024, 0, stream>>>(binsC, startC, NC);
    place_k<<<2048, 256, 0, stream>>>(cm_src, cm_dst, startM, curM, srt_cm, NE);
    place_k<<<2048, 256, 0, stream>>>(mc_src, mc_dst, startC, curC, srt_mc, NE);

    // layer 1: aggregate means (no atomics), then dense
    agg_k<<<(NM + 3) / 4, 256, 0, stream>>>(x_c, startM, srt_cm, agg_m, NM);
    agg_k<<<(NC + 3) / 4, 256, 0, stream>>>(x_m, startC, srt_mc, agg_c, NC);
    dense1_k<<<1024, 256, 0, stream>>>(agg_m, x_m, Wl1_cm, Wr1_cm, b1_cm, agg_m /*h_m alias*/, NM);
    dense1_k<<<2048, 256, 0, stream>>>(agg_c, x_c, Wl1_mc, Wr1_mc, b1_mc, h_c, NC);

    // layer 2: re-aggregate h_m over mc edges (reuse sorted list), fused dense2+linear
    agg_k<<<(NC + 3) / 4, 256, 0, stream>>>(agg_m /*h_m*/, startC, srt_mc, agg_c, NC);
    dense2_k<<<2048, 256, 0, stream>>>(agg_c, h_c, Wl2_mc, Wr2_mc, b2_mc,
                                       W_lin, b_lin, out, NC);
}

// Round 3
// 922.555 us; speedup vs baseline: 3.2807x; 1.4064x over previous
//
#include <hip/hip_runtime.h>

#define NC 200000
#define NM 50000
#define NE 1000000
#define DF 64   // feature dim (D == H == 64)

#define SCAN_B 512
#define SCAN_T 256

// ---------------- histogram: bins[dst[e]] += 1 (int atomics) ----------------
__global__ __launch_bounds__(256) void hist_k(const int* __restrict__ dst,
                                              int* __restrict__ bins, int n_edges) {
    int tid = blockIdx.x * blockDim.x + threadIdx.x;
    for (int e = tid; e < n_edges; e += gridDim.x * blockDim.x) {
        atomicAdd(&bins[dst[e]], 1);
    }
}

// ---------------- 3-phase device-wide exclusive scan ----------------
// phase 1: per-block partial sums (contiguous chunks)
__global__ __launch_bounds__(SCAN_T) void scan_part_k(const int* __restrict__ bins,
                                                      int* __restrict__ partials, int n) {
    __shared__ int red[SCAN_T];
    const int ch = (n + SCAN_B * SCAN_T - 1) / (SCAN_B * SCAN_T);
    const int t = threadIdx.x;
    const long base = ((long)blockIdx.x * SCAN_T + t) * ch;
    int s = 0;
    for (int i = 0; i < ch; ++i) {
        long idx = base + i;
        if (idx < n) s += bins[idx];
    }
    red[t] = s;
    __syncthreads();
    for (int off = SCAN_T / 2; off > 0; off >>= 1) {
        if (t < off) red[t] += red[t + off];
        __syncthreads();
    }
    if (t == 0) partials[blockIdx.x] = red[0];
}

// phase 2: single block scans the SCAN_B partials -> exclusive block offsets; writes start[n]=total
__global__ __launch_bounds__(SCAN_B) void scan_mid_k(const int* __restrict__ partials,
                                                     int* __restrict__ boff,
                                                     int* __restrict__ start, int n) {
    __shared__ int s[SCAN_B];
    const int t = threadIdx.x;
    s[t] = partials[t];
    __syncthreads();
    for (int off = 1; off < SCAN_B; off <<= 1) {
        int v = 0;
        if (t >= off) v = s[t - off];
        __syncthreads();
        if (t >= off) s[t] += v;
        __syncthreads();
    }
    boff[t] = (t == 0) ? 0 : s[t - 1];
    if (t == SCAN_B - 1) start[n] = s[t];
}

// phase 3: block-local scan + write exclusive prefixes
__global__ __launch_bounds__(SCAN_T) void scan_fin_k(const int* __restrict__ bins,
                                                     const int* __restrict__ boff,
                                                     int* __restrict__ start, int n) {
    __shared__ int red[SCAN_T];
    const int ch = (n + SCAN_B * SCAN_T - 1) / (SCAN_B * SCAN_T);
    const int t = threadIdx.x;
    const long base = ((long)blockIdx.x * SCAN_T + t) * ch;
    int s = 0;
    for (int i = 0; i < ch; ++i) {
        long idx = base + i;
        if (idx < n) s += bins[idx];
    }
    red[t] = s;
    __syncthreads();
    for (int off = 1; off < SCAN_T; off <<= 1) {
        int v = 0;
        if (t >= off) v = red[t - off];
        __syncthreads();
        if (t >= off) red[t] += v;
        __syncthreads();
    }
    int run = boff[blockIdx.x] + ((t == 0) ? 0 : red[t - 1]);
    for (int i = 0; i < ch; ++i) {
        long idx = base + i;
        if (idx < n) {
            start[idx] = run;
            run += bins[idx];
        }
    }
}

// ---------------- placement: sorted_src[start[d] + cur[d]++] = src[e] ----------------
__global__ __launch_bounds__(256) void place_k(const int* __restrict__ src,
                                               const int* __restrict__ dst,
                                               const int* __restrict__ start,
                                               int* __restrict__ cur,
                                               int* __restrict__ sorted_src, int n_edges) {
    int tid = blockIdx.x * blockDim.x + threadIdx.x;
    for (int e = tid; e < n_edges; e += gridDim.x * blockDim.x) {
        int d = dst[e];
        int pos = start[d] + atomicAdd(&cur[d], 1);
        sorted_src[pos] = src[e];
    }
}

// ---------------- aggregation: one wave per dst node, lane = feature ----------------
// writes the MEAN row directly (no atomics, no count array needed)
__global__ __launch_bounds__(256) void agg_k(const float* __restrict__ x,
                                             const int* __restrict__ start,
                                             const int* __restrict__ sorted_src,
                                             float* __restrict__ aggmean, int n_nodes) {
    const int wid = (blockIdx.x * blockDim.x + threadIdx.x) >> 6;
    const int lane = threadIdx.x & 63;
    const int nwaves = (gridDim.x * blockDim.x) >> 6;
    for (int n = wid; n < n_nodes; n += nwaves) {
        const int s0 = start[n];
        const int s1 = start[n + 1];
        float acc = 0.0f;
        for (int e = s0; e < s1; ++e) {
            int s = sorted_src[e];  // wave-uniform -> scalar/broadcast load
            acc += x[(long)s * DF + lane];
        }
        const float inv = 1.0f / fmaxf((float)(s1 - s0), 1.0f);
        aggmean[(long)n * DF + lane] = acc * inv;
    }
}

// ---------------- dense1: h = relu(mean @ Wl + x @ Wr + b) ----------------
__global__ __launch_bounds__(256) void dense1_k(const float* __restrict__ mean,
                                                const float* __restrict__ xdst,
                                                const float* __restrict__ Wl,
                                                const float* __restrict__ Wr,
                                                const float* __restrict__ b,
                                                float* __restrict__ hout, int n_nodes) {
    __shared__ float sWl[DF * DF];
    __shared__ float sWr[DF * DF];
    __shared__ float sAgg[4][DF];
    __shared__ float sX[4][DF];
    const int t = threadIdx.x;
    for (int i = t; i < DF * DF; i += 256) {
        sWl[i] = Wl[i];
        sWr[i] = Wr[i];
    }
    const int ln = t >> 6;   // local node 0..3
    const int j = t & 63;    // output feature
    const float bj = b[j];
    for (int node0 = blockIdx.x * 4; node0 < n_nodes; node0 += gridDim.x * 4) {
        const int node = node0 + ln;
        __syncthreads();              // covers weight load (iter 0) + prev-iter reads
        sAgg[ln][j] = mean[(long)node * DF + j];
        sX[ln][j] = xdst[(long)node * DF + j];
        __syncthreads();
        float acc = bj;
#pragma unroll
        for (int k = 0; k < DF; ++k) {
            acc = fmaf(sAgg[ln][k], sWl[k * DF + j], acc);
            acc = fmaf(sX[ln][k], sWr[k * DF + j], acc);
        }
        hout[(long)node * DF + j] = fmaxf(acc, 0.0f);  // relu
    }
}

// ---------------- dense2 + final linear fused ----------------
__global__ __launch_bounds__(256) void dense2_k(const float* __restrict__ mean,
                                                const float* __restrict__ hc,
                                                const float* __restrict__ Wl,
                                                const float* __restrict__ Wr,
                                                const float* __restrict__ b,
                                                const float* __restrict__ Wlin,
                                                const float* __restrict__ blin,
                                                float* __restrict__ out, int n_nodes) {
    __shared__ float sWl[DF * DF];
    __shared__ float sWr[DF * DF];
    __shared__ float sAgg[4][DF];
    __shared__ float sH[4][DF];
    const int t = threadIdx.x;
    for (int i = t; i < DF * DF; i += 256) {
        sWl[i] = Wl[i];
        sWr[i] = Wr[i];
    }
    const int ln = t >> 6;
    const int j = t & 63;
    const float bj = b[j];
    const float wl0 = Wlin[j * 2 + 0];
    const float wl1 = Wlin[j * 2 + 1];
    const float bl0 = blin[0];
    const float bl1 = blin[1];
    for (int node0 = blockIdx.x * 4; node0 < n_nodes; node0 += gridDim.x * 4) {
        const int node = node0 + ln;
        __syncthreads();
        sAgg[ln][j] = mean[(long)node * DF + j];
        sH[ln][j] = hc[(long)node * DF + j];
        __syncthreads();
        float acc = bj;
#pragma unroll
        for (int k = 0; k < DF; ++k) {
            acc = fmaf(sAgg[ln][k], sWl[k * DF + j], acc);
            acc = fmaf(sH[ln][k], sWr[k * DF + j], acc);
        }
        float r0 = acc * wl0;
        float r1 = acc * wl1;
#pragma unroll
        for (int off = 32; off > 0; off >>= 1) {
            r0 += __shfl_xor(r0, off);
            r1 += __shfl_xor(r1, off);
        }
        if (j == 0) {
            out[(long)node * 2 + 0] = r0 + bl0;
            out[(long)node * 2 + 1] = r1 + bl1;
        }
    }
}

extern "C" void kernel_launch(void* const* d_in, const int* in_sizes, int n_in,
                              void* d_out, int out_size, void* d_ws, size_t ws_size,
                              hipStream_t stream) {
    const float* x_c = (const float*)d_in[0];
    const float* x_m = (const float*)d_in[1];
    const int* cm_src = (const int*)d_in[2];
    const int* cm_dst = (const int*)d_in[3];
    const int* mc_src = (const int*)d_in[4];
    const int* mc_dst = (const int*)d_in[5];
    const float* Wl1_cm = (const float*)d_in[6];
    const float* Wr1_cm = (const float*)d_in[7];
    const float* b1_cm = (const float*)d_in[8];
    const float* Wl1_mc = (const float*)d_in[9];
    const float* Wr1_mc = (const float*)d_in[10];
    const float* b1_mc = (const float*)d_in[11];
    // layer-2 cm weights (d_in[12..14]) are dead: h2_m is unused in the reference
    const float* Wl2_mc = (const float*)d_in[15];
    const float* Wr2_mc = (const float*)d_in[16];
    const float* b2_mc = (const float*)d_in[17];
    const float* W_lin = (const float*)d_in[18];
    const float* b_lin = (const float*)d_in[19];
    float* out = (float*)d_out;

    // ---- workspace layout ----
    float* ws = (float*)d_ws;
    float* agg_m = ws;                             // layer-1 m-mean, then h_m (aliased)
    float* h_c = agg_m + (long)NM * DF;
    float* agg_c = h_c + (long)NC * DF;            // layer-1 c-mean, reused for layer-2 c-mean
    int* ip = (int*)(agg_c + (long)NC * DF);
    int* binsM = ip;
    int* binsC = binsM + NM;
    int* curM = binsC + NC;
    int* curC = curM + NM;
    int* startM = curC + NC;
    int* startC = startM + (NM + 1);
    int* srt_cm = startC + (NC + 1);
    int* srt_mc = srt_cm + NE;
    int* partM = srt_mc + NE;
    int* boffM = partM + SCAN_B;
    int* partC = boffM + SCAN_B;
    int* boffC = partC + SCAN_B;

    // zero bins + cursors (contiguous)
    hipMemsetAsync(binsM, 0, (size_t)(2 * (NM + NC)) * sizeof(int), stream);

    // build CSR grouping by destination for both edge types
    hist_k<<<2048, 256, 0, stream>>>(cm_dst, binsM, NE);
    hist_k<<<2048, 256, 0, stream>>>(mc_dst, binsC, NE);

    scan_part_k<<<SCAN_B, SCAN_T, 0, stream>>>(binsM, partM, NM);
    scan_mid_k<<<1, SCAN_B, 0, stream>>>(partM, boffM, startM, NM);
    scan_fin_k<<<SCAN_B, SCAN_T, 0, stream>>>(binsM, boffM, startM, NM);

    scan_part_k<<<SCAN_B, SCAN_T, 0, stream>>>(binsC, partC, NC);
    scan_mid_k<<<1, SCAN_B, 0, stream>>>(partC, boffC, startC, NC);
    scan_fin_k<<<SCAN_B, SCAN_T, 0, stream>>>(binsC, boffC, startC, NC);

    place_k<<<2048, 256, 0, stream>>>(cm_src, cm_dst, startM, curM, srt_cm, NE);
    place_k<<<2048, 256, 0, stream>>>(mc_src, mc_dst, startC, curC, srt_mc, NE);

    // layer 1: aggregate means (no atomics), then dense
    agg_k<<<(NM + 3) / 4, 256, 0, stream>>>(x_c, startM, srt_cm, agg_m, NM);
    agg_k<<<(NC + 3) / 4, 256, 0, stream>>>(x_m, startC, srt_mc, agg_c, NC);
    dense1_k<<<1024, 256, 0, stream>>>(agg_m, x_m, Wl1_cm, Wr1_cm, b1_cm, agg_m /*h_m alias*/, NM);
    dense1_k<<<2048, 256, 0, stream>>>(agg_c, x_c, Wl1_mc, Wr1_mc, b1_mc, h_c, NC);

    // layer 2: re-aggregate h_m over mc edges (reuse sorted list), fused dense2+linear
    agg_k<<<(NC + 3) / 4, 256, 0, stream>>>(agg_m /*h_m*/, startC, srt_mc, agg_c, NC);
    dense2_k<<<2048, 256, 0, stream>>>(agg_c, h_c, Wl2_mc, Wr2_mc, b2_mc,
                                       W_lin, b_lin, out, NC);
}

// Round 5
// 519.084 us; speedup vs baseline: 5.8307x; 1.7773x over previous
//
#include <hip/hip_runtime.h>

#define NC 200000
#define NM 50000
#define NE 1000000
#define DF 64   // feature dim (D == H == 64)

#define SCAN_B 512
#define SCAN_T 256

typedef __attribute__((ext_vector_type(8))) short bf16x8;
typedef __attribute__((ext_vector_type(4))) float f32x4;

// ---------------- histogram: bins[dst[e]] += 1 (int atomics) ----------------
__global__ __launch_bounds__(256) void hist_k(const int* __restrict__ dst,
                                              int* __restrict__ bins, int n_edges) {
    int tid = blockIdx.x * blockDim.x + threadIdx.x;
    for (int e = tid; e < n_edges; e += gridDim.x * blockDim.x) {
        atomicAdd(&bins[dst[e]], 1);
    }
}

// ---------------- 3-phase device-wide exclusive scan ----------------
__global__ __launch_bounds__(SCAN_T) void scan_part_k(const int* __restrict__ bins,
                                                      int* __restrict__ partials, int n) {
    __shared__ int red[SCAN_T];
    const int ch = (n + SCAN_B * SCAN_T - 1) / (SCAN_B * SCAN_T);
    const int t = threadIdx.x;
    const long base = ((long)blockIdx.x * SCAN_T + t) * ch;
    int s = 0;
    for (int i = 0; i < ch; ++i) {
        long idx = base + i;
        if (idx < n) s += bins[idx];
    }
    red[t] = s;
    __syncthreads();
    for (int off = SCAN_T / 2; off > 0; off >>= 1) {
        if (t < off) red[t] += red[t + off];
        __syncthreads();
    }
    if (t == 0) partials[blockIdx.x] = red[0];
}

__global__ __launch_bounds__(SCAN_B) void scan_mid_k(const int* __restrict__ partials,
                                                     int* __restrict__ boff,
                                                     int* __restrict__ start, int n) {
    __shared__ int s[SCAN_B];
    const int t = threadIdx.x;
    s[t] = partials[t];
    __syncthreads();
    for (int off = 1; off < SCAN_B; off <<= 1) {
        int v = 0;
        if (t >= off) v = s[t - off];
        __syncthreads();
        if (t >= off) s[t] += v;
        __syncthreads();
    }
    boff[t] = (t == 0) ? 0 : s[t - 1];
    if (t == SCAN_B - 1) start[n] = s[t];
}

__global__ __launch_bounds__(SCAN_T) void scan_fin_k(const int* __restrict__ bins,
                                                     const int* __restrict__ boff,
                                                     int* __restrict__ start, int n) {
    __shared__ int red[SCAN_T];
    const int ch = (n + SCAN_B * SCAN_T - 1) / (SCAN_B * SCAN_T);
    const int t = threadIdx.x;
    const long base = ((long)blockIdx.x * SCAN_T + t) * ch;
    int s = 0;
    for (int i = 0; i < ch; ++i) {
        long idx = base + i;
        if (idx < n) s += bins[idx];
    }
    red[t] = s;
    __syncthreads();
    for (int off = 1; off < SCAN_T; off <<= 1) {
        int v = 0;
        if (t >= off) v = red[t - off];
        __syncthreads();
        if (t >= off) red[t] += v;
        __syncthreads();
    }
    int run = boff[blockIdx.x] + ((t == 0) ? 0 : red[t - 1]);
    for (int i = 0; i < ch; ++i) {
        long idx = base + i;
        if (idx < n) {
            start[idx] = run;
            run += bins[idx];
        }
    }
}

// ---------------- placement: sorted_src[start[d] + cur[d]++] = src[e] ----------------
__global__ __launch_bounds__(256) void place_k(const int* __restrict__ src,
                                               const int* __restrict__ dst,
                                               const int* __restrict__ start,
                                               int* __restrict__ cur,
                                               int* __restrict__ sorted_src, int n_edges) {
    int tid = blockIdx.x * blockDim.x + threadIdx.x;
    for (int e = tid; e < n_edges; e += gridDim.x * blockDim.x) {
        int d = dst[e];
        int pos = start[d] + atomicAdd(&cur[d], 1);
        sorted_src[pos] = src[e];
    }
}

// ---------------- aggregation: one wave per dst node, lane = feature ----------------
__global__ __launch_bounds__(256) void agg_k(const float* __restrict__ x,
                                             const int* __restrict__ start,
                                             const int* __restrict__ sorted_src,
                                             float* __restrict__ aggmean, int n_nodes) {
    const int wid = (blockIdx.x * blockDim.x + threadIdx.x) >> 6;
    const int lane = threadIdx.x & 63;
    const int nwaves = (gridDim.x * blockDim.x) >> 6;
    for (int n = wid; n < n_nodes; n += nwaves) {
        const int s0 = start[n];
        const int s1 = start[n + 1];
        float a0 = 0.0f, a1 = 0.0f, a2 = 0.0f, a3 = 0.0f;
        int e = s0;
        for (; e + 3 < s1; e += 4) {
            int i0 = sorted_src[e + 0];
            int i1 = sorted_src[e + 1];
            int i2 = sorted_src[e + 2];
            int i3 = sorted_src[e + 3];
            a0 += x[(long)i0 * DF + lane];
            a1 += x[(long)i1 * DF + lane];
            a2 += x[(long)i2 * DF + lane];
            a3 += x[(long)i3 * DF + lane];
        }
        for (; e < s1; ++e) a0 += x[(long)sorted_src[e] * DF + lane];
        const float acc = (a0 + a1) + (a2 + a3);
        const float inv = 1.0f / fmaxf((float)(s1 - s0), 1.0f);
        aggmean[(long)n * DF + lane] = acc * inv;
    }
}

// ---------------- round-to-nearest split-bf16 helpers ----------------
__device__ __forceinline__ short bf16rn(float x) {
    unsigned u = __builtin_bit_cast(unsigned, x);
    unsigned r = u + 0x7FFFu + ((u >> 16) & 1u);
    return (short)(r >> 16);
}
__device__ __forceinline__ float bf16f(short h) {
    unsigned u = ((unsigned)(unsigned short)h) << 16;
    return __builtin_bit_cast(float, u);
}
__device__ __forceinline__ void split8(const f32x4 u, const f32x4 v,
                                       bf16x8& hi, bf16x8& lo) {
#pragma unroll
    for (int b = 0; b < 4; ++b) {
        short h = bf16rn(u[b]);
        hi[b] = h;
        lo[b] = bf16rn(u[b] - bf16f(h));
    }
#pragma unroll
    for (int b = 0; b < 4; ++b) {
        short h = bf16rn(v[b]);
        hi[4 + b] = h;
        lo[4 + b] = bf16rn(v[b] - bf16f(h));
    }
}

#define MFMA(a, b, c) __builtin_amdgcn_mfma_f32_16x16x32_bf16((a), (b), (c), 0, 0, 0)

// 4-term exact-ish product: acc += (hi+lo)_A * (hi+lo)_B
#define MFMA4(ah, al, bh, bl, acc)      \
    do {                                \
        acc = MFMA(ah, bh, acc);        \
        acc = MFMA(ah, bl, acc);        \
        acc = MFMA(al, bh, acc);        \
        acc = MFMA(al, bl, acc);        \
    } while (0)

// ---------------- dense1 (MFMA): h = relu(mean @ Wl + x @ Wr + b) ----------------
// SAFE for hout aliasing mean: the mean tile is staged through LDS with a
// barrier before any store; each tile is owned by exactly one block.
// Block = 4 waves; wave wv handles column-tile wv; grid-stride over row tiles.
__global__ __launch_bounds__(256) void dense1_mfma(const float* __restrict__ mean,
                                                   const float* __restrict__ xdst,
                                                   const float* __restrict__ Wl,
                                                   const float* __restrict__ Wr,
                                                   const float* __restrict__ bias,
                                                   float* __restrict__ hout, int n_nodes) {
    __shared__ float sA[16][68];   // +4 pad: fragment reads ~conflict-free
    const int t = threadIdx.x;
    const int lane = t & 63;
    const int wv = t >> 6;               // 0..3 = column tile
    const int col = wv * 16 + (lane & 15);
    const int g = lane >> 4;

    bf16x8 wlh[2], wll[2], wrh[2], wrl[2];
#pragma unroll
    for (int q = 0; q < 2; ++q) {
        f32x4 tl0, tl1, tr0, tr1;
#pragma unroll
        for (int b = 0; b < 4; ++b) {
            int k = 32 * q + 8 * g + b;
            tl0[b] = Wl[k * DF + col];
            tr0[b] = Wr[k * DF + col];
            tl1[b] = Wl[(k + 4) * DF + col];
            tr1[b] = Wr[(k + 4) * DF + col];
        }
        split8(tl0, tl1, wlh[q], wll[q]);
        split8(tr0, tr1, wrh[q], wrl[q]);
    }
    const float bv = bias[col];

    const int srow = t >> 4;            // staging: thread -> (row, 4-col chunk)
    const int sc4 = (t & 15) * 4;
    const int nrt = n_nodes >> 4;

    for (int rt = blockIdx.x; rt < nrt; rt += gridDim.x) {
        // stage mean tile (the potentially-aliased operand) into LDS
        *(f32x4*)&sA[srow][sc4] =
            *(const f32x4*)(mean + ((long)rt * 16 + srow) * DF + sc4);
        // x row fragments straight from global (never aliased)
        const float* xrow = xdst + ((long)rt * 16 + (lane & 15)) * DF + 8 * g;
        const f32x4 xu0 = *(const f32x4*)(xrow + 0);
        const f32x4 xv0 = *(const f32x4*)(xrow + 4);
        const f32x4 xu1 = *(const f32x4*)(xrow + 32);
        const f32x4 xv1 = *(const f32x4*)(xrow + 36);
        __syncthreads();   // tile fully staged before anyone computes/stores

        const int ar = lane & 15;
        const f32x4 au0 = *(const f32x4*)&sA[ar][8 * g + 0];
        const f32x4 av0 = *(const f32x4*)&sA[ar][8 * g + 4];
        const f32x4 au1 = *(const f32x4*)&sA[ar][8 * g + 32];
        const f32x4 av1 = *(const f32x4*)&sA[ar][8 * g + 36];

        f32x4 acc = {0.f, 0.f, 0.f, 0.f};
        bf16x8 h, l;
        split8(au0, av0, h, l);
        MFMA4(h, l, wlh[0], wll[0], acc);
        split8(au1, av1, h, l);
        MFMA4(h, l, wlh[1], wll[1], acc);
        split8(xu0, xv0, h, l);
        MFMA4(h, l, wrh[0], wrl[0], acc);
        split8(xu1, xv1, h, l);
        MFMA4(h, l, wrh[1], wrl[1], acc);

#pragma unroll
        for (int r = 0; r < 4; ++r) {
            float v = fmaxf(acc[r] + bv, 0.0f);
            hout[((long)rt * 16 + 4 * g + r) * DF + col] = v;
        }
        __syncthreads();   // all LDS reads done before next iter's staging
    }
}

// ---------------- dense2 (MFMA) + fused final linear ----------------
// h2 = mean @ Wl + hc @ Wr + b (no relu); out[node] += h2 @ Wlin (+ blin from wave ct==0)
// No aliasing here -> direct global reads, no barriers.
__global__ __launch_bounds__(256) void dense2_mfma(const float* __restrict__ mean,
                                                   const float* __restrict__ hc,
                                                   const float* __restrict__ Wl,
                                                   const float* __restrict__ Wr,
                                                   const float* __restrict__ bias,
                                                   const float* __restrict__ Wlin,
                                                   const float* __restrict__ blin,
                                                   float* __restrict__ out, int n_nodes) {
    const int wglobal = (blockIdx.x * blockDim.x + threadIdx.x) >> 6;
    const int lane = threadIdx.x & 63;
    const int nwaves = (gridDim.x * blockDim.x) >> 6;
    const int ct = wglobal & 3;
    const int col = ct * 16 + (lane & 15);
    const int g = lane >> 4;

    bf16x8 wlh[2], wll[2], wrh[2], wrl[2];
#pragma unroll
    for (int q = 0; q < 2; ++q) {
        f32x4 tl0, tl1, tr0, tr1;
#pragma unroll
        for (int b = 0; b < 4; ++b) {
            int k = 32 * q + 8 * g + b;
            tl0[b] = Wl[k * DF + col];
            tr0[b] = Wr[k * DF + col];
            tl1[b] = Wl[(k + 4) * DF + col];
            tr1[b] = Wr[(k + 4) * DF + col];
        }
        split8(tl0, tl1, wlh[q], wll[q]);
        split8(tr0, tr1, wrh[q], wrl[q]);
    }
    const float bv = bias[col];
    const float wl0 = Wlin[col * 2 + 0];
    const float wl1 = Wlin[col * 2 + 1];
    const float bl0 = (ct == 0) ? blin[0] : 0.0f;
    const float bl1 = (ct == 0) ? blin[1] : 0.0f;

    const int nrt = n_nodes >> 4;
    for (int rt = wglobal >> 2; rt < nrt; rt += nwaves >> 2) {
        const float* arow = mean + ((long)rt * 16 + (lane & 15)) * DF + 8 * g;
        const float* hrow = hc + ((long)rt * 16 + (lane & 15)) * DF + 8 * g;
        f32x4 acc = {0.f, 0.f, 0.f, 0.f};
        bf16x8 h, l;
        split8(*(const f32x4*)(arow + 0), *(const f32x4*)(arow + 4), h, l);
        MFMA4(h, l, wlh[0], wll[0], acc);
        split8(*(const f32x4*)(arow + 32), *(const f32x4*)(arow + 36), h, l);
        MFMA4(h, l, wlh[1], wll[1], acc);
        split8(*(const f32x4*)(hrow + 0), *(const f32x4*)(hrow + 4), h, l);
        MFMA4(h, l, wrh[0], wrl[0], acc);
        split8(*(const f32x4*)(hrow + 32), *(const f32x4*)(hrow + 36), h, l);
        MFMA4(h, l, wrh[1], wrl[1], acc);

#pragma unroll
        for (int r = 0; r < 4; ++r) {
            float h2 = acc[r] + bv;
            float p0 = h2 * wl0;
            float p1 = h2 * wl1;
#pragma unroll
            for (int m = 1; m < 16; m <<= 1) {
                p0 += __shfl_xor(p0, m);
                p1 += __shfl_xor(p1, m);
            }
            if ((lane & 15) == 0) {
                long node = (long)rt * 16 + 4 * g + r;
                atomicAdd(&out[node * 2 + 0], p0 + bl0);
                atomicAdd(&out[node * 2 + 1], p1 + bl1);
            }
        }
    }
}

extern "C" void kernel_launch(void* const* d_in, const int* in_sizes, int n_in,
                              void* d_out, int out_size, void* d_ws, size_t ws_size,
                              hipStream_t stream) {
    const float* x_c = (const float*)d_in[0];
    const float* x_m = (const float*)d_in[1];
    const int* cm_src = (const int*)d_in[2];
    const int* cm_dst = (const int*)d_in[3];
    const int* mc_src = (const int*)d_in[4];
    const int* mc_dst = (const int*)d_in[5];
    const float* Wl1_cm = (const float*)d_in[6];
    const float* Wr1_cm = (const float*)d_in[7];
    const float* b1_cm = (const float*)d_in[8];
    const float* Wl1_mc = (const float*)d_in[9];
    const float* Wr1_mc = (const float*)d_in[10];
    const float* b1_mc = (const float*)d_in[11];
    // layer-2 cm weights (d_in[12..14]) are dead: h2_m is unused in the reference
    const float* Wl2_mc = (const float*)d_in[15];
    const float* Wr2_mc = (const float*)d_in[16];
    const float* b2_mc = (const float*)d_in[17];
    const float* W_lin = (const float*)d_in[18];
    const float* b_lin = (const float*)d_in[19];
    float* out = (float*)d_out;

    // ---- workspace layout ----
    float* ws = (float*)d_ws;
    float* agg_m = ws;                             // layer-1 m-mean, then h_m (in-place, race-safe)
    float* h_c = agg_m + (long)NM * DF;
    float* agg_c = h_c + (long)NC * DF;            // layer-1 c-mean, reused for layer-2 c-mean
    int* ip = (int*)(agg_c + (long)NC * DF);
    int* binsM = ip;
    int* binsC = binsM + NM;
    int* curM = binsC + NC;
    int* curC = curM + NM;
    int* startM = curC + NC;
    int* startC = startM + (NM + 1);
    int* srt_cm = startC + (NC + 1);
    int* srt_mc = srt_cm + NE;
    int* partM = srt_mc + NE;
    int* boffM = partM + SCAN_B;
    int* partC = boffM + SCAN_B;
    int* boffC = partC + SCAN_B;

    // zero bins + cursors (contiguous), and the atomically-accumulated output
    hipMemsetAsync(binsM, 0, (size_t)(2 * (NM + NC)) * sizeof(int), stream);
    hipMemsetAsync(out, 0, (size_t)out_size * sizeof(float), stream);

    // build CSR grouping by destination for both edge types
    hist_k<<<2048, 256, 0, stream>>>(cm_dst, binsM, NE);
    hist_k<<<2048, 256, 0, stream>>>(mc_dst, binsC, NE);

    scan_part_k<<<SCAN_B, SCAN_T, 0, stream>>>(binsM, partM, NM);
    scan_mid_k<<<1, SCAN_B, 0, stream>>>(partM, boffM, startM, NM);
    scan_fin_k<<<SCAN_B, SCAN_T, 0, stream>>>(binsM, boffM, startM, NM);

    scan_part_k<<<SCAN_B, SCAN_T, 0, stream>>>(binsC, partC, NC);
    scan_mid_k<<<1, SCAN_B, 0, stream>>>(partC, boffC, startC, NC);
    scan_fin_k<<<SCAN_B, SCAN_T, 0, stream>>>(binsC, boffC, startC, NC);

    place_k<<<2048, 256, 0, stream>>>(cm_src, cm_dst, startM, curM, srt_cm, NE);
    place_k<<<2048, 256, 0, stream>>>(mc_src, mc_dst, startC, curC, srt_mc, NE);

    // layer 1: aggregate means (no atomics), then MFMA dense
    agg_k<<<(NM + 3) / 4, 256, 0, stream>>>(x_c, startM, srt_cm, agg_m, NM);
    agg_k<<<(NC + 3) / 4, 256, 0, stream>>>(x_m, startC, srt_mc, agg_c, NC);
    dense1_mfma<<<1024, 256, 0, stream>>>(agg_m, x_m, Wl1_cm, Wr1_cm, b1_cm, agg_m /*h_m alias*/, NM);
    dense1_mfma<<<2048, 256, 0, stream>>>(agg_c, x_c, Wl1_mc, Wr1_mc, b1_mc, h_c, NC);

    // layer 2: re-aggregate h_m over mc edges (reuse sorted list), fused dense2+linear
    agg_k<<<(NC + 3) / 4, 256, 0, stream>>>(agg_m /*h_m*/, startC, srt_mc, agg_c, NC);
    dense2_mfma<<<2048, 256, 0, stream>>>(agg_c, h_c, Wl2_mc, Wr2_mc, b2_mc,
                                          W_lin, b_lin, out, NC);
}